// Round 8
// baseline (218.627 us; speedup 1.0000x reference)
//
#include <hip/hip_runtime.h>
#include <math.h>

// ---------------------------------------------------------------------------
// KAN-Conv CIFAR net on gfx950, round 13.
// r12's L3 counters (48us, VALUBusy 36%, occ 33%, HBM 4%) pin the conv
// bottleneck on per-tap weight fetch: lane-divergent per-tap global loads
// (8 cache lines/request at FS=16), serialized by unroll-1. Fix: make
// (fh,og) WAVE-UNIFORM by splitting pool positions across lanes (PS), so
// weight loads become wave-uniform scalar (SGPR/SMEM) loads via
// readfirstlane -> zero VMEM-vector and zero LDS cost for weights; FMAs
// read weights from SGPRs. Act LDS reads/tap drop to 6 (PS=2) / 3 (PS=4).
//  - L2: VS=2, PS=2, FS=2, GO=4, NT=512, grid 512 -> 16 waves/CU.
//  - L3: VS=1, OS=2, PS=4, FS=2, GO=4, NT=512, grid 512 -> 16 waves/CU.
//  - pool-max via shfl_xor(16/32); FS=2 reduce via 8-16KB LDS round.
//  - kx fully unrolled (no VMEM hoisting to fence anymore).
// L1 (WLDS + inline w2/w3 prep) and linear_coop are r11-verbatim (155.2us).
// ---------------------------------------------------------------------------

#define BATCH 256

struct W3 { float x, y, z; };   // packed 12-byte LDS record

__device__ __forceinline__ void bspline_basis(float x, float bs[6]) {
    const float h = 2.0f / 3.0f;
    float g[10];
#pragma unroll
    for (int i = 0; i < 10; ++i) g[i] = (float)(i - 3) * h - 1.0f;
    float b[9];
#pragma unroll
    for (int i = 0; i < 9; ++i) b[i] = (x >= g[i] && x < g[i + 1]) ? 1.0f : 0.0f;
#pragma unroll
    for (int j = 1; j <= 3; ++j) {
        const float inv_d = 1.0f / ((float)j * h);
#pragma unroll
        for (int i = 0; i + j < 9; ++i) {
            float left  = (x - g[i]) * inv_d;
            float right = (g[i + j + 1] - x) * inv_d;
            b[i] = left * b[i] + right * b[i + 1];
        }
    }
#pragma unroll
    for (int i = 0; i < 6; ++i) bs[i] = b[i];
}

// ---------------------------------------------------------------------------
// L1 kernel (r11-verbatim): WLDS own weights + inline prep of w2/w3.
// ---------------------------------------------------------------------------
template <int C, int O, int GO, int H, int W, int VS, int OS, int FS, int NT,
          int MINW, int WLDS, int PREP>
__global__ __launch_bounds__(NT, MINW) void kan_conv_pool(
        const float* __restrict__ x,
        const float* __restrict__ wrec,
        const float* __restrict__ rbw, const float* __restrict__ rsw, const float* __restrict__ rsc,
        const float* __restrict__ p2bw, const float* __restrict__ p2sw, const float* __restrict__ p2sc,
        const float* __restrict__ p3bw, const float* __restrict__ p3sw, const float* __restrict__ p3sc,
        float* __restrict__ w2dst, float* __restrict__ w3dst,
        float* __restrict__ out) {
    constexpr int PH = H / 2, PW = W / 2;
    constexpr int PR = PH / VS;
    constexpr int R  = 2 * PR + 2;
    constexpr int TC = W + 2;
    constexpr int CP = TC / 2;
    constexpr int F  = C * 9;
    constexpr int PPB = PR * PW;
    constexpr int OPB = O / OS;
    constexpr int NOG = OPB / GO;
    constexpr int CS = C / FS;
    constexpr int CPLANE = R * 2 * CP;
    constexpr int HALF = C * CPLANE;
    static_assert(NT == NOG * FS * PPB, "thread mapping");
    static_assert(FS * CS == C, "channel split");
    static_assert(NOG * GO == OPB && OPB * OS == O, "o split");

    constexpr int ACT_BYTES = HALF * 28;
    constexpr int RED_BYTES = (FS > 1) ? NT * GO * 16 : 0;
    constexpr int ARENA = ACT_BYTES > RED_BYTES ? ACT_BYTES : RED_BYTES;
    static_assert(RED_BYTES <= ARENA, "red fits");
    __shared__ alignas(16) unsigned char s_mem[ARENA];
    float4* s_lo = (float4*)s_mem;
    W3*     s_hi = (W3*)(s_mem + (size_t)HALF * 16);
    constexpr int NWR = WLDS ? O * F : 1;
    __shared__ float4 s_wlo[NWR];
    __shared__ W3     s_whi[NWR];

    const int tid = threadIdx.x;
    const int bid = blockIdx.x;

    if (PREP) {
        int i = bid * NT + tid;
        if (i < 5760) {
            const float *bw, *sw, *sc;
            float* dst;
            int j, OO, FF;
            if (i < 1152) { bw = p2bw; sw = p2sw; sc = p2sc; dst = w2dst; j = i;        OO = 16; FF = 72;  }
            else          { bw = p3bw; sw = p3sw; sc = p3sc; dst = w3dst; j = i - 1152; OO = 32; FF = 144; }
            int o = j / FF, fi = j % FF;
            float s = sc[j];
            float4* dq = (float4*)(dst + (size_t)(fi * OO + o) * 8);
            dq[0] = make_float4(bw[j], sw[j * 6 + 0] * s, sw[j * 6 + 1] * s, sw[j * 6 + 2] * s);
            dq[1] = make_float4(sw[j * 6 + 3] * s, sw[j * 6 + 4] * s, sw[j * 6 + 5] * s, 0.0f);
        }
    }

    if (WLDS) {
        for (int j = tid; j < O * F; j += NT) {
            int o = j / F, fi = j % F;
            float s = rsc[j];
            int r = fi * O + o;
            s_wlo[r] = make_float4(rbw[j], rsw[j * 6 + 0] * s, rsw[j * 6 + 1] * s, rsw[j * 6 + 2] * s);
            W3 t; t.x = rsw[j * 6 + 3] * s; t.y = rsw[j * 6 + 4] * s; t.z = rsw[j * 6 + 5] * s;
            s_whi[r] = t;
        }
    }

    const int b   = bid / (VS * OS);
    const int rem = bid % (VS * OS);
    const int v   = rem / OS;
    const int osb = rem % OS;
    const int r0 = v * (2 * PR) - 1;

    const float* xb = x + (size_t)b * C * H * W;
    for (int i = tid; i < C * R * TC; i += NT) {
        int cc  = i / (R * TC);
        int rr  = (i / TC) % R;
        int col = i % TC;
        int gr = r0 + rr, gc = col - 1;
        float val = 0.0f;
        if ((unsigned)gr < (unsigned)H && (unsigned)gc < (unsigned)W)
            val = xb[(cc * H + gr) * W + gc];
        float silu = val / (1.0f + __expf(-val));
        float bs[6];
        bspline_basis(val, bs);
        int idx = ((cc * R + rr) * 2 + (col & 1)) * CP + (col >> 1);
        s_lo[idx] = make_float4(silu, bs[0], bs[1], bs[2]);
        W3 t; t.x = bs[3]; t.y = bs[4]; t.z = bs[5];
        s_hi[idx] = t;
    }
    __syncthreads();

    const int px = tid % PPB;
    const int fh = (tid / PPB) % FS;
    const int og = tid / (PPB * FS);
    const int phl = px / PW, pw = px % PW;
    const int o0 = osb * OPB + og * GO;

    float acc[GO][4];
#pragma unroll
    for (int g = 0; g < GO; ++g)
#pragma unroll
        for (int p = 0; p < 4; ++p) acc[g][p] = 0.f;

    const int pbase = (2 * phl) * (2 * CP) + pw;

#pragma unroll 1
    for (int cc = 0; cc < CS; ++cc) {
        const int c = fh * CS + cc;
        const float4* plo = s_lo + c * CPLANE;
        const W3*     phi = s_hi + c * CPLANE;
#pragma unroll 1
        for (int ky = 0; ky < 3; ++ky) {
#pragma unroll 1
            for (int kx = 0; kx < 3; ++kx) {
                const int f = c * 9 + ky * 3 + kx;
                float4 wl[GO];
                float  whx[GO], why[GO], whz[GO];
                if (WLDS) {
                    const int rb = f * O + o0;
#pragma unroll
                    for (int g = 0; g < GO; ++g) {
                        wl[g] = s_wlo[rb + g];
                        W3 t = s_whi[rb + g];
                        whx[g] = t.x; why[g] = t.y; whz[g] = t.z;
                    }
                } else {
                    const float4* wp = (const float4*)wrec + (size_t)(f * O + o0) * 2;
#pragma unroll
                    for (int g = 0; g < GO; ++g) {
                        wl[g] = wp[g * 2];
                        float4 hv = wp[g * 2 + 1];
                        whx[g] = hv.x; why[g] = hv.y; whz[g] = hv.z;
                    }
                }
#pragma unroll
                for (int dy = 0; dy < 2; ++dy) {
#pragma unroll
                    for (int dx = 0; dx < 2; ++dx) {
                        const int s = dx + kx;
                        const int off = pbase + ((dy + ky) * 2 + (s & 1)) * CP + (s >> 1);
                        float4 lo = plo[off];
                        W3     hi = phi[off];
#pragma unroll
                        for (int g = 0; g < GO; ++g) {
                            acc[g][dy * 2 + dx] +=
                                lo.x * wl[g].x + lo.y * wl[g].y + lo.z * wl[g].z +
                                lo.w * wl[g].w + hi.x * whx[g] + hi.y * why[g] +
                                hi.z * whz[g];
                        }
                    }
                }
            }
        }
    }

    const int phg = v * PR + phl;

    if (FS > 1) {
        float4* s_red = (float4*)s_mem;
        __syncthreads();
#pragma unroll
        for (int g = 0; g < GO; ++g)
            s_red[g * NT + tid] = make_float4(acc[g][0], acc[g][1], acc[g][2], acc[g][3]);
        __syncthreads();
        if (fh != 0) return;
#pragma unroll
        for (int fq = 1; fq < FS; ++fq)
#pragma unroll
            for (int g = 0; g < GO; ++g) {
                float4 t = s_red[g * NT + tid + fq * PPB];
                acc[g][0] += t.x; acc[g][1] += t.y; acc[g][2] += t.z; acc[g][3] += t.w;
            }
#pragma unroll
        for (int g = 0; g < GO; ++g) {
            float m = fmaxf(fmaxf(acc[g][0], acc[g][1]), fmaxf(acc[g][2], acc[g][3]));
            out[(((size_t)b * O + o0 + g) * PH + phg) * PW + pw] = m;
        }
    } else {
#pragma unroll
        for (int g = 0; g < GO; ++g) {
            float m = fmaxf(fmaxf(acc[g][0], acc[g][1]), fmaxf(acc[g][2], acc[g][3]));
            out[(((size_t)b * O + o0 + g) * PH + phg) * PW + pw] = m;
        }
    }
}

// ---------------------------------------------------------------------------
// PS kernel (L2/L3): pool positions split across lanes so (fh,og) are
// wave-uniform -> weight loads are SGPR scalar loads. PS=2: lane = px(PPB)
// x dy(2). PS=4: lane = px(PPB) x pos(4).
// ---------------------------------------------------------------------------
template <int C, int O, int GO, int H, int W, int VS, int OS, int FS, int PS,
          int NT, int MINW>
__global__ __launch_bounds__(NT, MINW) void kan_conv_ps(
        const float* __restrict__ x,
        const float* __restrict__ wrec,
        float* __restrict__ out) {
    constexpr int PH = H / 2, PW = W / 2;
    constexpr int PR = PH / VS;
    constexpr int R  = 2 * PR + 2;
    constexpr int TC = W + 2;
    constexpr int CP = TC / 2;
    constexpr int F  = C * 9;
    constexpr int PPB = PR * PW;           // pooled px per block
    constexpr int OPB = O / OS;
    constexpr int NOG = OPB / GO;
    constexpr int CS = C / FS;
    constexpr int CPLANE = R * 2 * CP;
    constexpr int HALF = C * CPLANE;
    constexpr int NPP = 4 / PS;            // pool positions per thread
    static_assert(PPB * PS == 64, "wave = px x pos");
    static_assert(NT == NOG * FS * 64, "thread mapping");
    static_assert(FS * CS == C, "channel split");
    static_assert(NOG * GO == OPB && OPB * OS == O, "o split");
    static_assert(PS == 2 || PS == 4, "PS");

    constexpr int ACT_BYTES = HALF * 28;
    constexpr int RED_BYTES = (FS > 1) ? NT * GO * NPP * 4 : 0;
    constexpr int ARENA = ACT_BYTES > RED_BYTES ? ACT_BYTES : RED_BYTES;
    __shared__ alignas(16) unsigned char s_mem[ARENA];
    float4* s_lo = (float4*)s_mem;
    W3*     s_hi = (W3*)(s_mem + (size_t)HALF * 16);

    const int tid = threadIdx.x;
    const int bid = blockIdx.x;
    const int b   = bid / (VS * OS);
    const int rem = bid % (VS * OS);
    const int v   = rem / OS;
    const int osb = rem % OS;
    const int r0 = v * (2 * PR) - 1;

    // ---- Stage acts
    const float* xb = x + (size_t)b * C * H * W;
    for (int i = tid; i < C * R * TC; i += NT) {
        int cc  = i / (R * TC);
        int rr  = (i / TC) % R;
        int col = i % TC;
        int gr = r0 + rr, gc = col - 1;
        float val = 0.0f;
        if ((unsigned)gr < (unsigned)H && (unsigned)gc < (unsigned)W)
            val = xb[(cc * H + gr) * W + gc];
        float silu = val / (1.0f + __expf(-val));
        float bs[6];
        bspline_basis(val, bs);
        int idx = ((cc * R + rr) * 2 + (col & 1)) * CP + (col >> 1);
        s_lo[idx] = make_float4(silu, bs[0], bs[1], bs[2]);
        W3 t; t.x = bs[3]; t.y = bs[4]; t.z = bs[5];
        s_hi[idx] = t;
    }
    __syncthreads();

    // ---- Mapping: lane = px + PPB*pos; wave wv -> (fh, og) uniform.
    const int lane = tid & 63;
    const int wv   = tid >> 6;
    const int px   = lane % PPB;
    const int pos  = lane / PPB;
    const int fh   = wv % FS;
    const int og   = wv / FS;
    const int phl = px / PW, pw = px % PW;
    // Force SGPR provenance for the weight row base.
    const int o0 = __builtin_amdgcn_readfirstlane(osb * OPB + og * GO);

    const int dy0   = (PS == 2) ? pos : (pos >> 1);
    const int dxfix = (PS == 4) ? (pos & 1) : 0;
    const int rowbase = (2 * phl + dy0) * (2 * CP) + pw;

    float acc[GO][NPP];
#pragma unroll
    for (int g = 0; g < GO; ++g)
#pragma unroll
        for (int p = 0; p < NPP; ++p) acc[g][p] = 0.f;

#pragma unroll 1
    for (int cc = 0; cc < CS; ++cc) {
        const int c = fh * CS + cc;
        const float4* plo = s_lo + c * CPLANE;
        const W3*     phi = s_hi + c * CPLANE;
#pragma unroll 1
        for (int ky = 0; ky < 3; ++ky) {
#pragma unroll
            for (int kx = 0; kx < 3; ++kx) {
                const int f = c * 9 + ky * 3 + kx;
                const float4* wq = (const float4*)wrec + ((size_t)(f * O + o0)) * 2;
                float4 wl[GO];
                float  whx[GO], why[GO], whz[GO];
#pragma unroll
                for (int g = 0; g < GO; ++g) {
                    wl[g] = wq[g * 2];
                    float4 hv = wq[g * 2 + 1];
                    whx[g] = hv.x; why[g] = hv.y; whz[g] = hv.z;
                }
                if (PS == 2) {
#pragma unroll
                    for (int dx = 0; dx < 2; ++dx) {
                        const int s = dx + kx;
                        const int off = rowbase + ky * (2 * CP) + (s & 1) * CP + (s >> 1);
                        float4 lo = plo[off];
                        W3     hi = phi[off];
#pragma unroll
                        for (int g = 0; g < GO; ++g) {
                            acc[g][dx] +=
                                lo.x * wl[g].x + lo.y * wl[g].y + lo.z * wl[g].z +
                                lo.w * wl[g].w + hi.x * whx[g] + hi.y * why[g] +
                                hi.z * whz[g];
                        }
                    }
                } else {
                    const int s = dxfix + kx;
                    const int off = rowbase + ky * (2 * CP) + (s & 1) * CP + (s >> 1);
                    float4 lo = plo[off];
                    W3     hi = phi[off];
#pragma unroll
                    for (int g = 0; g < GO; ++g) {
                        acc[g][0] +=
                            lo.x * wl[g].x + lo.y * wl[g].y + lo.z * wl[g].z +
                            lo.w * wl[g].w + hi.x * whx[g] + hi.y * why[g] +
                            hi.z * whz[g];
                    }
                }
            }
        }
    }

    // ---- FS reduction (fh-partials; partner waves 64*fq apart in tid)
    if (FS > 1) {
        float* s_red = (float*)s_mem;
        __syncthreads();                   // act reads done before overwrite
        if (fh != 0) {
#pragma unroll
            for (int g = 0; g < GO; ++g)
#pragma unroll
                for (int p = 0; p < NPP; ++p)
                    s_red[(g * NPP + p) * NT + tid] = acc[g][p];
        }
        __syncthreads();
        if (fh == 0) {
#pragma unroll
            for (int fq = 1; fq < FS; ++fq)
#pragma unroll
                for (int g = 0; g < GO; ++g)
#pragma unroll
                    for (int p = 0; p < NPP; ++p)
                        acc[g][p] += s_red[(g * NPP + p) * NT + tid + 64 * fq];
        }
    }

    // ---- pool-max across lanes + store (wave-uniform branch; shfl safe)
    if (fh == 0) {
        const int phg = v * PR + phl;
#pragma unroll
        for (int g = 0; g < GO; ++g) {
            float m;
            if (PS == 2) {
                m = fmaxf(acc[g][0], acc[g][1]);
                m = fmaxf(m, __shfl_xor(m, 32));
            } else {
                m = acc[g][0];
                m = fmaxf(m, __shfl_xor(m, 16));
                m = fmaxf(m, __shfl_xor(m, 32));
            }
            if (pos == 0)
                out[(((size_t)b * O + o0 + g) * PH + phg) * PW + pw] = m;
        }
    }
}

// Wave-cooperative linear (r11-verbatim).
__global__ __launch_bounds__(256) void linear_coop(const float* __restrict__ h,
                                                   const float* __restrict__ w,
                                                   const float* __restrict__ bias,
                                                   float* __restrict__ out) {
    const int n = blockIdx.x;
    const int tid = threadIdx.x;
    const int lane = tid & 63;
    const int wv = tid >> 6;

    __shared__ float4 s_h[128];
    if (tid < 128) s_h[tid] = ((const float4*)(h + (size_t)n * 512))[tid];
    __syncthreads();

    const float4 h0 = s_h[lane];
    const float4 h1 = s_h[lane + 64];

#pragma unroll 1
    for (int i = 0; i < 25; ++i) {
        const int o = wv * 25 + i;
        const float4* wr = (const float4*)(w + (size_t)o * 512);
        float4 w0 = wr[lane];
        float4 w1 = wr[lane + 64];
        float p = w0.x * h0.x + w0.y * h0.y + w0.z * h0.z + w0.w * h0.w
                + w1.x * h1.x + w1.y * h1.y + w1.z * h1.z + w1.w * h1.w;
        p += __shfl_xor(p, 32);
        p += __shfl_xor(p, 16);
        p += __shfl_xor(p, 8);
        p += __shfl_xor(p, 4);
        p += __shfl_xor(p, 2);
        p += __shfl_xor(p, 1);
        if (lane == 0) out[(size_t)n * 100 + o] = p + bias[o];
    }
}

extern "C" void kernel_launch(void* const* d_in, const int* in_sizes, int n_in,
                              void* d_out, int out_size, void* d_ws, size_t ws_size,
                              hipStream_t stream) {
    const float* x     = (const float*)d_in[0];
    const float* c1_bw = (const float*)d_in[1];
    const float* c1_sw = (const float*)d_in[2];
    const float* c1_sc = (const float*)d_in[3];
    const float* c2_bw = (const float*)d_in[4];
    const float* c2_sw = (const float*)d_in[5];
    const float* c2_sc = (const float*)d_in[6];
    const float* c3_bw = (const float*)d_in[7];
    const float* c3_sw = (const float*)d_in[8];
    const float* c3_sc = (const float*)d_in[9];
    const float* lin_w = (const float*)d_in[10];
    const float* lin_b = (const float*)d_in[11];
    float* out = (float*)d_out;

    float* ws = (float*)d_ws;
    float* h1 = ws;                 // 256*8*16*16  = 524288
    float* h2 = h1 + 524288;        // 256*16*8*8   = 262144
    float* h3 = h2 + 262144;        // 256*32*4*4   = 131072
    float* w2 = h3 + 131072;        // 1152*8 = 9216
    float* w3 = w2 + 9216;          // 4608*8 = 36864

    // L1: WLDS + inline w2/w3 prep (r11-verbatim). 512 blocks x 768.
    kan_conv_pool<3, 8, 4, 32, 32, 2, 1, 3, 768, 4, 1, 1><<<512, 768, 0, stream>>>(
        x, nullptr,
        c1_bw, c1_sw, c1_sc,
        c2_bw, c2_sw, c2_sc,
        c3_bw, c3_sw, c3_sc,
        w2, w3, h1);
    // L2: [256,8,16,16] -> [256,16,8,8]; PS=2, FS=2, GO=4, VS=2.
    // 512 blocks x 512 -> 2 blocks/CU, 16 waves/CU; SGPR weights.
    kan_conv_ps<8, 16, 4, 16, 16, 2, 1, 2, 2, 512, 4><<<512, 512, 0, stream>>>(
        h1, w2, h2);
    // L3: [256,16,8,8] -> [256,32,4,4]; PS=4, FS=2, GO=4, OS=2.
    // 512 blocks x 512 -> 2 blocks/CU, 16 waves/CU; SGPR weights.
    kan_conv_ps<16, 32, 4, 8, 8, 1, 2, 2, 4, 512, 4><<<512, 512, 0, stream>>>(
        h2, w3, h3);
    // Linear: block per n, coalesced w reads.
    linear_coop<<<256, 256, 0, stream>>>(h3, lin_w, lin_b, out);
}

// Round 9
// 163.595 us; speedup vs baseline: 1.3364x; 1.3364x over previous
//
#include <hip/hip_runtime.h>
#include <math.h>

// ---------------------------------------------------------------------------
// KAN-Conv CIFAR net on gfx950, round 14.
// History: best = r11 (155.2us). r12 (GO=8+occupancy) and r13 (SGPR weights
// + pool-split) both REGRESSED -> restructures of the proven body lose;
// config/data-format changes win. Surviving model: conv inner loop is bound
// by LDS-pipe THROUGHPUT (~12cyc per ds_read_b128/b96, m134): 8-16 reads per
// wave-tap vs 224/4 = 56 CU-cyc of FMA -> 1.5-3.4x oversubscribed.
// This round: r11 VERBATIM except act records (and L1's LDS weights) packed
// as bf16x8 in ONE uint4 -> 1 ds_read_b128 per record (was 2: b128+b96).
//  - acts [silu,b0..b5] -> 7 bf16 + pad, unpack = 7 shifts/ands.
//  - L1 WLDS weights same packing (16->8 LDS reads/wave-tap).
//  - L2/L3 weights unchanged (global f32 float4 pairs, VMEM pipe).
//  - arenas shrink 28/16: L2 40.5KB, L3 32KB.
// Accuracy: bf16 acts everywhere + bf16 L1 weights -> absmax ~2-8e-3,
// threshold 2.45e-2 (sized for bf16 compute; floor_eps_k=8).
// ---------------------------------------------------------------------------

#define BATCH 256

__device__ __forceinline__ unsigned f2bf(float f) {
    unsigned u = __float_as_uint(f);
    u += 0x7fffu + ((u >> 16) & 1u);       // round-to-nearest-even
    return u >> 16;
}
__device__ __forceinline__ unsigned pk2(float a, float b) {
    return f2bf(a) | (f2bf(b) << 16);
}
__device__ __forceinline__ void unpack7(uint4 v, float a[7]) {
    a[0] = __uint_as_float(v.x << 16);
    a[1] = __uint_as_float(v.x & 0xffff0000u);
    a[2] = __uint_as_float(v.y << 16);
    a[3] = __uint_as_float(v.y & 0xffff0000u);
    a[4] = __uint_as_float(v.z << 16);
    a[5] = __uint_as_float(v.z & 0xffff0000u);
    a[6] = __uint_as_float(v.w << 16);
}

__device__ __forceinline__ void bspline_basis(float x, float bs[6]) {
    const float h = 2.0f / 3.0f;
    float g[10];
#pragma unroll
    for (int i = 0; i < 10; ++i) g[i] = (float)(i - 3) * h - 1.0f;
    float b[9];
#pragma unroll
    for (int i = 0; i < 9; ++i) b[i] = (x >= g[i] && x < g[i + 1]) ? 1.0f : 0.0f;
#pragma unroll
    for (int j = 1; j <= 3; ++j) {
        const float inv_d = 1.0f / ((float)j * h);
#pragma unroll
        for (int i = 0; i + j < 9; ++i) {
            float left  = (x - g[i]) * inv_d;
            float right = (g[i + j + 1] - x) * inv_d;
            b[i] = left * b[i] + right * b[i + 1];
        }
    }
#pragma unroll
    for (int i = 0; i < 6; ++i) bs[i] = b[i];
}

// Fused: basis precompute (LDS, bf16-packed) + KAN conv3x3(pad1) + maxpool2.
// x: [B,C,H,W]; wrec: [C*9, O, 8] fused f32 (tap-major); out: [B,O,H/2,W/2].
// VS: vertical split. OS: output-channel split. FS: channel split in block.
// WLDS: build this layer's fused weights (bf16-packed) in LDS from raw.
// PREP: first blocks also fuse the OTHER layers' f32 weights to global.
template <int C, int O, int GO, int H, int W, int VS, int OS, int FS, int NT,
          int MINW, int WLDS, int PREP>
__global__ __launch_bounds__(NT, MINW) void kan_conv_pool(
        const float* __restrict__ x,
        const float* __restrict__ wrec,
        const float* __restrict__ rbw, const float* __restrict__ rsw, const float* __restrict__ rsc,
        const float* __restrict__ p2bw, const float* __restrict__ p2sw, const float* __restrict__ p2sc,
        const float* __restrict__ p3bw, const float* __restrict__ p3sw, const float* __restrict__ p3sc,
        float* __restrict__ w2dst, float* __restrict__ w3dst,
        float* __restrict__ out) {
    constexpr int PH = H / 2, PW = W / 2;
    constexpr int PR = PH / VS;
    constexpr int R  = 2 * PR + 2;
    constexpr int TC = W + 2;
    constexpr int CP = TC / 2;
    constexpr int F  = C * 9;
    constexpr int PPB = PR * PW;
    constexpr int OPB = O / OS;
    constexpr int NOG = OPB / GO;
    constexpr int CS = C / FS;
    constexpr int CPLANE = R * 2 * CP;
    constexpr int HALF = C * CPLANE;
    static_assert(NT == NOG * FS * PPB, "thread mapping");
    static_assert(FS * CS == C, "channel split");
    static_assert(NOG * GO == OPB && OPB * OS == O, "o split");

    constexpr int ACT_BYTES = HALF * 16;   // one uint4 per record
    constexpr int RED_BYTES = (FS > 1) ? NT * GO * 16 : 0;
    constexpr int ARENA = ACT_BYTES > RED_BYTES ? ACT_BYTES : RED_BYTES;
    static_assert(RED_BYTES <= ARENA, "red fits");
    __shared__ alignas(16) unsigned char s_mem[ARENA];
    uint4* s_act = (uint4*)s_mem;
    constexpr int NWR = WLDS ? O * F : 1;
    __shared__ uint4 s_wq[NWR];

    const int tid = threadIdx.x;
    const int bid = blockIdx.x;

    // ---- Inline prep of other layers' fused f32 weights (first blocks).
    if (PREP) {
        int i = bid * NT + tid;
        if (i < 5760) {
            const float *bw, *sw, *sc;
            float* dst;
            int j, OO, FF;
            if (i < 1152) { bw = p2bw; sw = p2sw; sc = p2sc; dst = w2dst; j = i;        OO = 16; FF = 72;  }
            else          { bw = p3bw; sw = p3sw; sc = p3sc; dst = w3dst; j = i - 1152; OO = 32; FF = 144; }
            int o = j / FF, fi = j % FF;
            float s = sc[j];
            float4* dq = (float4*)(dst + (size_t)(fi * OO + o) * 8);
            dq[0] = make_float4(bw[j], sw[j * 6 + 0] * s, sw[j * 6 + 1] * s, sw[j * 6 + 2] * s);
            dq[1] = make_float4(sw[j * 6 + 3] * s, sw[j * 6 + 4] * s, sw[j * 6 + 5] * s, 0.0f);
        }
    }

    // ---- Own-layer fused weights into LDS, bf16-packed (r = f*O + o).
    if (WLDS) {
        for (int j = tid; j < O * F; j += NT) {
            int o = j / F, fi = j % F;
            float s = rsc[j];
            uint4 r;
            r.x = pk2(rbw[j],          rsw[j * 6 + 0] * s);
            r.y = pk2(rsw[j * 6 + 1] * s, rsw[j * 6 + 2] * s);
            r.z = pk2(rsw[j * 6 + 3] * s, rsw[j * 6 + 4] * s);
            r.w = f2bf(rsw[j * 6 + 5] * s);
            s_wq[fi * O + o] = r;
        }
    }

    const int b   = bid / (VS * OS);
    const int rem = bid % (VS * OS);
    const int v   = rem / OS;
    const int osb = rem % OS;
    const int r0 = v * (2 * PR) - 1;

    // ---- Stage: zero-padded x -> bf16x8 [silu, b0..b5, pad] records
    const float* xb = x + (size_t)b * C * H * W;
    for (int i = tid; i < C * R * TC; i += NT) {
        int cc  = i / (R * TC);
        int rr  = (i / TC) % R;
        int col = i % TC;
        int gr = r0 + rr, gc = col - 1;
        float val = 0.0f;
        if ((unsigned)gr < (unsigned)H && (unsigned)gc < (unsigned)W)
            val = xb[(cc * H + gr) * W + gc];
        float silu = val / (1.0f + __expf(-val));
        float bs[6];
        bspline_basis(val, bs);
        int idx = ((cc * R + rr) * 2 + (col & 1)) * CP + (col >> 1);
        uint4 r;
        r.x = pk2(silu, bs[0]);
        r.y = pk2(bs[1], bs[2]);
        r.z = pk2(bs[3], bs[4]);
        r.w = f2bf(bs[5]);
        s_act[idx] = r;
    }
    __syncthreads();

    // ---- Thread mapping (r11-verbatim)
    const int px = tid % PPB;
    const int fh = (tid / PPB) % FS;
    const int og = tid / (PPB * FS);
    const int phl = px / PW, pw = px % PW;
    const int o0 = osb * OPB + og * GO;

    float acc[GO][4];
#pragma unroll
    for (int g = 0; g < GO; ++g)
#pragma unroll
        for (int p = 0; p < 4; ++p) acc[g][p] = 0.f;

    const int pbase = (2 * phl) * (2 * CP) + pw;

#pragma unroll 1
    for (int cc = 0; cc < CS; ++cc) {
        const int c = fh * CS + cc;
        const uint4* pact = s_act + c * CPLANE;
#pragma unroll 1
        for (int ky = 0; ky < 3; ++ky) {
#pragma unroll 1
            for (int kx = 0; kx < 3; ++kx) {
                const int f = c * 9 + ky * 3 + kx;
                float wf[GO][7];
                if (WLDS) {
                    const int rb = f * O + o0;
#pragma unroll
                    for (int g = 0; g < GO; ++g)
                        unpack7(s_wq[rb + g], wf[g]);
                } else {
                    const float4* wp = (const float4*)wrec + (size_t)(f * O + o0) * 2;
#pragma unroll
                    for (int g = 0; g < GO; ++g) {
                        float4 lo = wp[g * 2];
                        float4 hv = wp[g * 2 + 1];
                        wf[g][0] = lo.x; wf[g][1] = lo.y; wf[g][2] = lo.z;
                        wf[g][3] = lo.w; wf[g][4] = hv.x; wf[g][5] = hv.y;
                        wf[g][6] = hv.z;
                    }
                }
#pragma unroll
                for (int dy = 0; dy < 2; ++dy) {
#pragma unroll
                    for (int dx = 0; dx < 2; ++dx) {
                        const int s = dx + kx;
                        const int off = pbase + ((dy + ky) * 2 + (s & 1)) * CP + (s >> 1);
                        float a[7];
                        unpack7(pact[off], a);
#pragma unroll
                        for (int g = 0; g < GO; ++g) {
                            acc[g][dy * 2 + dx] +=
                                a[0] * wf[g][0] + a[1] * wf[g][1] + a[2] * wf[g][2] +
                                a[3] * wf[g][3] + a[4] * wf[g][4] + a[5] * wf[g][5] +
                                a[6] * wf[g][6];
                        }
                    }
                }
            }
        }
    }

    const int phg = v * PR + phl;

    if (FS > 1) {
        float4* s_red = (float4*)s_mem;
        __syncthreads();                   // act reads done before overwrite
#pragma unroll
        for (int g = 0; g < GO; ++g)
            s_red[g * NT + tid] = make_float4(acc[g][0], acc[g][1], acc[g][2], acc[g][3]);
        __syncthreads();
        if (fh != 0) return;
#pragma unroll
        for (int fq = 1; fq < FS; ++fq)
#pragma unroll
            for (int g = 0; g < GO; ++g) {
                float4 t = s_red[g * NT + tid + fq * PPB];
                acc[g][0] += t.x; acc[g][1] += t.y; acc[g][2] += t.z; acc[g][3] += t.w;
            }
#pragma unroll
        for (int g = 0; g < GO; ++g) {
            float m = fmaxf(fmaxf(acc[g][0], acc[g][1]), fmaxf(acc[g][2], acc[g][3]));
            out[(((size_t)b * O + o0 + g) * PH + phg) * PW + pw] = m;
        }
    } else {
#pragma unroll
        for (int g = 0; g < GO; ++g) {
            float m = fmaxf(fmaxf(acc[g][0], acc[g][1]), fmaxf(acc[g][2], acc[g][3]));
            out[(((size_t)b * O + o0 + g) * PH + phg) * PW + pw] = m;
        }
    }
}

// Wave-cooperative linear (r11-verbatim): block per n; h3[n] in LDS; wave
// owns 25 outputs; w[o] rows read coalesced; shfl_xor reduce.
__global__ __launch_bounds__(256) void linear_coop(const float* __restrict__ h,
                                                   const float* __restrict__ w,
                                                   const float* __restrict__ bias,
                                                   float* __restrict__ out) {
    const int n = blockIdx.x;
    const int tid = threadIdx.x;
    const int lane = tid & 63;
    const int wv = tid >> 6;

    __shared__ float4 s_h[128];
    if (tid < 128) s_h[tid] = ((const float4*)(h + (size_t)n * 512))[tid];
    __syncthreads();

    const float4 h0 = s_h[lane];
    const float4 h1 = s_h[lane + 64];

#pragma unroll 1
    for (int i = 0; i < 25; ++i) {
        const int o = wv * 25 + i;
        const float4* wr = (const float4*)(w + (size_t)o * 512);
        float4 w0 = wr[lane];
        float4 w1 = wr[lane + 64];
        float p = w0.x * h0.x + w0.y * h0.y + w0.z * h0.z + w0.w * h0.w
                + w1.x * h1.x + w1.y * h1.y + w1.z * h1.z + w1.w * h1.w;
        p += __shfl_xor(p, 32);
        p += __shfl_xor(p, 16);
        p += __shfl_xor(p, 8);
        p += __shfl_xor(p, 4);
        p += __shfl_xor(p, 2);
        p += __shfl_xor(p, 1);
        if (lane == 0) out[(size_t)n * 100 + o] = p + bias[o];
    }
}

extern "C" void kernel_launch(void* const* d_in, const int* in_sizes, int n_in,
                              void* d_out, int out_size, void* d_ws, size_t ws_size,
                              hipStream_t stream) {
    const float* x     = (const float*)d_in[0];
    const float* c1_bw = (const float*)d_in[1];
    const float* c1_sw = (const float*)d_in[2];
    const float* c1_sc = (const float*)d_in[3];
    const float* c2_bw = (const float*)d_in[4];
    const float* c2_sw = (const float*)d_in[5];
    const float* c2_sc = (const float*)d_in[6];
    const float* c3_bw = (const float*)d_in[7];
    const float* c3_sw = (const float*)d_in[8];
    const float* c3_sc = (const float*)d_in[9];
    const float* lin_w = (const float*)d_in[10];
    const float* lin_b = (const float*)d_in[11];
    float* out = (float*)d_out;

    float* ws = (float*)d_ws;
    float* h1 = ws;                 // 256*8*16*16  = 524288
    float* h2 = h1 + 524288;        // 256*16*8*8   = 262144
    float* h3 = h2 + 262144;        // 256*32*4*4   = 131072
    float* w2 = h3 + 131072;        // 1152*8 = 9216
    float* w3 = w2 + 9216;          // 4608*8 = 36864

    // L1: WLDS(bf16) + inline w2/w3 prep. 512 blocks x 768. (r11 config)
    kan_conv_pool<3, 8, 4, 32, 32, 2, 1, 3, 768, 4, 1, 1><<<512, 768, 0, stream>>>(
        x, nullptr,
        c1_bw, c1_sw, c1_sc,
        c2_bw, c2_sw, c2_sc,
        c3_bw, c3_sw, c3_sc,
        w2, w3, h1);
    // L2: [256,8,16,16] -> [256,16,8,8]; GO=4, FS=4, NT=512. 512 blocks.
    kan_conv_pool<8, 16, 4, 16, 16, 2, 1, 4, 512, 4, 0, 0><<<512, 512, 0, stream>>>(
        h1, w2,
        nullptr, nullptr, nullptr,
        nullptr, nullptr, nullptr,
        nullptr, nullptr, nullptr,
        nullptr, nullptr, h2);
    // L3: [256,16,8,8] -> [256,32,4,4]; OS=2, GO=4, FS=8, NT=512. 512 blocks.
    kan_conv_pool<16, 32, 4, 8, 8, 1, 2, 8, 512, 4, 0, 0><<<512, 512, 0, stream>>>(
        h2, w3,
        nullptr, nullptr, nullptr,
        nullptr, nullptr, nullptr,
        nullptr, nullptr, nullptr,
        nullptr, nullptr, h3);
    // Linear: block per n, coalesced w reads.
    linear_coop<<<256, 256, 0, stream>>>(h3, lin_w, lin_b, out);
}

// Round 10
// 123.169 us; speedup vs baseline: 1.7750x; 1.3282x over previous
//
#include <hip/hip_runtime.h>
#include <math.h>

// ---------------------------------------------------------------------------
// KAN-Conv CIFAR net on gfx950, round 15: MFMA rewrite.
// Scalar path is exhausted (r7/r8/r12/r13/r14 all null-or-worse around the
// 155-175us band). Each conv layer is a GEMM: out[px,o] = sum_k act[px,k]*w[k,o],
// k = (c,tap,basis0..7pad) -> K = C*9*8 (L1 224 incl 1 zero pad-tap, L2 576,
// L3 1152). One mfma_f32_16x16x32_bf16 A-fragment lane-group = exactly one
// bf16x8 act record (1 ds_read_b128); B = tap-major bf16 weight records,
// preloaded to VGPRs (NS steps x 4). Record feature order identical on both
// operands -> any within-k permutation cancels. C/D layout (verified, m89):
// col=lane&15 (=o), row=(lane>>4)*4+reg (=x) -> maxpool x-pairs are in-lane
// reg pairs; y-pairs in-lane (row-pair tiles) or shfl_xor(32) (L3).
//  - L1: C=3 O=8(pad16) 32x32, VS=2, grid 512 x 512thr, LDS 36.5KB.
//  - L2: C=8 O=16 16x16, grid 256 x 512thr, LDS 59.9KB.
//  - L3: C=16 O=32 8x8, OS=2 (o-half per block), grid 512 x 256thr, 62.5KB.
//  - weights fused (sw*sc, bw) from raw per block -> no prep kernel.
// Linear: r11's proven linear_coop.
// ---------------------------------------------------------------------------

#define BATCH 256

typedef short bf16x8 __attribute__((ext_vector_type(8)));
typedef float f32x4  __attribute__((ext_vector_type(4)));

__device__ __forceinline__ unsigned f2bf(float f) {
    unsigned u = __float_as_uint(f);
    u += 0x7fffu + ((u >> 16) & 1u);       // round-to-nearest-even
    return u >> 16;
}
__device__ __forceinline__ unsigned pk2(float a, float b) {
    return f2bf(a) | (f2bf(b) << 16);
}

__device__ __forceinline__ void bspline_basis(float x, float bs[6]) {
    const float h = 2.0f / 3.0f;
    float g[10];
#pragma unroll
    for (int i = 0; i < 10; ++i) g[i] = (float)(i - 3) * h - 1.0f;
    float b[9];
#pragma unroll
    for (int i = 0; i < 9; ++i) b[i] = (x >= g[i] && x < g[i + 1]) ? 1.0f : 0.0f;
#pragma unroll
    for (int j = 1; j <= 3; ++j) {
        const float inv_d = 1.0f / ((float)j * h);
#pragma unroll
        for (int i = 0; i + j < 9; ++i) {
            float left  = (x - g[i]) * inv_d;
            float right = (g[i + j + 1] - x) * inv_d;
            b[i] = left * b[i] + right * b[i + 1];
        }
    }
#pragma unroll
    for (int i = 0; i < 6; ++i) bs[i] = b[i];
}

// [silu, b0..b5, 0] as 8 bf16 in one uint4.
__device__ __forceinline__ uint4 act_record(float val) {
    float silu = val / (1.0f + __expf(-val));
    float bs[6];
    bspline_basis(val, bs);
    uint4 r;
    r.x = pk2(silu, bs[0]);
    r.y = pk2(bs[1], bs[2]);
    r.z = pk2(bs[3], bs[4]);
    r.w = f2bf(bs[5]);
    return r;
}

// One kernel template for all three conv+pool layers.
template <int LAYER>
__global__ __launch_bounds__(LAYER == 3 ? 256 : 512, LAYER == 1 ? 4 : 2)
void kan_mfma(const float* __restrict__ x,
              const float* __restrict__ bw, const float* __restrict__ sw,
              const float* __restrict__ sc,
              float* __restrict__ out) {
    constexpr int C  = (LAYER == 1) ? 3 : (LAYER == 2) ? 8 : 16;
    constexpr int O  = (LAYER == 1) ? 8 : (LAYER == 2) ? 16 : 32;
    constexpr int H  = (LAYER == 1) ? 32 : (LAYER == 2) ? 16 : 8;
    constexpr int W  = H;
    constexpr int F  = C * 9;                      // real taps
    constexpr int FP = (LAYER == 1) ? 28 : F;      // padded taps (mult of 4)
    constexpr int NS = FP / 4;                     // K-steps (K=32 per step)
    constexpr int VS = (LAYER == 1) ? 2 : 1;       // vertical image split
    constexpr int RT = H / VS + 2;                 // staged rows incl halo
    constexpr int TC = W + 2;                      // staged cols incl halo
    constexpr int NT = (LAYER == 3) ? 256 : 512;
    constexpr int NTILE = (LAYER == 1) ? 4 : (LAYER == 2) ? 2 : 1;
    constexpr int PH = H / 2, PW = W / 2;

    __shared__ uint4 s_act[C * RT * TC];           // act records
    __shared__ uint4 s_w[FP * 16];                 // weight records [tap][o]

    const int tid = threadIdx.x;
    const int bid = blockIdx.x;
    const int b   = (LAYER == 2) ? bid : (bid >> 1);
    const int v   = (LAYER == 1) ? (bid & 1) : 0;
    const int o0  = (LAYER == 3) ? 16 * (bid & 1) : 0;

    // ---- Stage fused bf16 weight records [fp][oc] (zeros for padding)
    for (int i = tid; i < FP * 16; i += NT) {
        int fp = i >> 4, oc_ = i & 15;
        int o = o0 + oc_;
        uint4 r = make_uint4(0u, 0u, 0u, 0u);
        if (fp < F && o < O) {
            int j = o * F + fp;
            float s = sc[j];
            r.x = pk2(bw[j],           sw[j * 6 + 0] * s);
            r.y = pk2(sw[j * 6 + 1] * s, sw[j * 6 + 2] * s);
            r.z = pk2(sw[j * 6 + 3] * s, sw[j * 6 + 4] * s);
            r.w = f2bf(sw[j * 6 + 5] * s);
        }
        s_w[i] = r;
    }

    // ---- Stage act records (zero-padded input; basis(0) for pad, matching ref)
    const int r0 = ((LAYER == 1) ? 16 * v : 0) - 1;
    const float* xb = x + (size_t)b * C * H * W;
    for (int i = tid; i < C * RT * TC; i += NT) {
        int cc  = i / (RT * TC);
        int rr  = (i / TC) % RT;
        int col = i % TC;
        int gr = r0 + rr, gc = col - 1;
        float val = 0.0f;
        if ((unsigned)gr < (unsigned)H && (unsigned)gc < (unsigned)W)
            val = xb[(cc * H + gr) * W + gc];
        s_act[i] = act_record(val);
    }
    __syncthreads();

    const int lane = tid & 63;
    const int wv   = tid >> 6;
    const int kg   = lane >> 4;                    // k-group 0..3
    const int oc   = lane & 15;                    // B col (output channel)
    const int m    = lane & 15;                    // A row (pixel in M-tile)

    // ---- Preload all B-fragments (weights) to registers
    bf16x8 bfr[NS];
#pragma unroll
    for (int s = 0; s < NS; ++s)
        bfr[s] = *reinterpret_cast<const bf16x8*>(&s_w[(4 * s + kg) * 16 + oc]);

    // ---- Per-tile pixel offsets (record index of pixel m in the M-tile)
    int pixoff[NTILE];
    if constexpr (LAYER == 1) {
        // wave wv: rows 2wv, 2wv+1; x-halves 0-15, 16-31
#pragma unroll
        for (int t = 0; t < 4; ++t)
            pixoff[t] = (2 * wv + (t >> 1)) * TC + 16 * (t & 1) + m;
    } else if constexpr (LAYER == 2) {
        pixoff[0] = (2 * wv) * TC + m;             // row 2wv
        pixoff[1] = (2 * wv + 1) * TC + m;         // row 2wv+1
    } else {
        // M-tile wv: rows 2wv,2wv+1 (8 px each); m = row*8 + x
        pixoff[0] = (2 * wv + (m >> 3)) * TC + (m & 7);
    }

    f32x4 acc[NTILE];
#pragma unroll
    for (int t = 0; t < NTILE; ++t) acc[t] = (f32x4){0.f, 0.f, 0.f, 0.f};

    // ---- K-loop: one A ds_read_b128 + one MFMA per (step, tile)
#pragma unroll
    for (int s = 0; s < NS; ++s) {
        int tp = 4 * s + kg;                       // tap index for this k-group
        if constexpr (FP != F) tp = (tp > F - 1) ? F - 1 : tp;  // L1 pad tap: B=0
        int c  = tp / 9;
        int t9 = tp - 9 * c;
        int ky = t9 / 3;
        int kx = t9 - 3 * ky;
        int base = (c * RT + ky) * TC + kx;
#pragma unroll
        for (int t = 0; t < NTILE; ++t) {
            bf16x8 a = *reinterpret_cast<const bf16x8*>(&s_act[base + pixoff[t]]);
            acc[t] = __builtin_amdgcn_mfma_f32_16x16x32_bf16(a, bfr[s], acc[t], 0, 0, 0);
        }
    }

    // ---- maxpool + store. D: col=lane&15 (=oc), row=(lane>>4)*4+reg (=x).
    const int g = kg;
    if constexpr (LAYER == 1) {
        if (oc < 8) {
            f32x4 e0, e1;
#pragma unroll
            for (int p = 0; p < 4; ++p) {
                e0[p] = fmaxf(acc[0][p], acc[2][p]);   // rows 2wv/2wv+1, x 0-15
                e1[p] = fmaxf(acc[1][p], acc[3][p]);   // x 16-31
            }
            float* op = out + (((size_t)b * 8 + oc) * 16 + (8 * v + wv)) * 16;
            op[2 * g]         = fmaxf(e0[0], e0[1]);
            op[2 * g + 1]     = fmaxf(e0[2], e0[3]);
            op[8 + 2 * g]     = fmaxf(e1[0], e1[1]);
            op[8 + 2 * g + 1] = fmaxf(e1[2], e1[3]);
        }
    } else if constexpr (LAYER == 2) {
        f32x4 e;
#pragma unroll
        for (int p = 0; p < 4; ++p) e[p] = fmaxf(acc[0][p], acc[1][p]);
        float* op = out + (((size_t)b * 16 + oc) * 8 + wv) * 8;
        op[2 * g]     = fmaxf(e[0], e[1]);
        op[2 * g + 1] = fmaxf(e[2], e[3]);
    } else {
        // in-lane x-pairs, then y across lane^32 (g 0<->2, 1<->3)
        float q0 = fmaxf(acc[0][0], acc[0][1]);
        float q1 = fmaxf(acc[0][2], acc[0][3]);
        float y0 = fmaxf(q0, __shfl_xor(q0, 32));
        float y1 = fmaxf(q1, __shfl_xor(q1, 32));
        if (g < 2) {
            float* op = out + (((size_t)b * 32 + o0 + oc) * 4 + wv) * 4;
            op[2 * g]     = y0;
            op[2 * g + 1] = y1;
        }
    }
}

// Wave-cooperative linear (r11-verbatim): block per n; h3[n] in LDS; wave
// owns 25 outputs; w[o] rows read coalesced; shfl_xor reduce.
__global__ __launch_bounds__(256) void linear_coop(const float* __restrict__ h,
                                                   const float* __restrict__ w,
                                                   const float* __restrict__ bias,
                                                   float* __restrict__ out) {
    const int n = blockIdx.x;
    const int tid = threadIdx.x;
    const int lane = tid & 63;
    const int wv = tid >> 6;

    __shared__ float4 s_h[128];
    if (tid < 128) s_h[tid] = ((const float4*)(h + (size_t)n * 512))[tid];
    __syncthreads();

    const float4 h0 = s_h[lane];
    const float4 h1 = s_h[lane + 64];

#pragma unroll 1
    for (int i = 0; i < 25; ++i) {
        const int o = wv * 25 + i;
        const float4* wr = (const float4*)(w + (size_t)o * 512);
        float4 w0 = wr[lane];
        float4 w1 = wr[lane + 64];
        float p = w0.x * h0.x + w0.y * h0.y + w0.z * h0.z + w0.w * h0.w
                + w1.x * h1.x + w1.y * h1.y + w1.z * h1.z + w1.w * h1.w;
        p += __shfl_xor(p, 32);
        p += __shfl_xor(p, 16);
        p += __shfl_xor(p, 8);
        p += __shfl_xor(p, 4);
        p += __shfl_xor(p, 2);
        p += __shfl_xor(p, 1);
        if (lane == 0) out[(size_t)n * 100 + o] = p + bias[o];
    }
}

extern "C" void kernel_launch(void* const* d_in, const int* in_sizes, int n_in,
                              void* d_out, int out_size, void* d_ws, size_t ws_size,
                              hipStream_t stream) {
    const float* x     = (const float*)d_in[0];
    const float* c1_bw = (const float*)d_in[1];
    const float* c1_sw = (const float*)d_in[2];
    const float* c1_sc = (const float*)d_in[3];
    const float* c2_bw = (const float*)d_in[4];
    const float* c2_sw = (const float*)d_in[5];
    const float* c2_sc = (const float*)d_in[6];
    const float* c3_bw = (const float*)d_in[7];
    const float* c3_sw = (const float*)d_in[8];
    const float* c3_sc = (const float*)d_in[9];
    const float* lin_w = (const float*)d_in[10];
    const float* lin_b = (const float*)d_in[11];
    float* out = (float*)d_out;

    float* ws = (float*)d_ws;
    float* h1 = ws;                 // 256*8*16*16  = 524288
    float* h2 = h1 + 524288;        // 256*16*8*8   = 262144
    float* h3 = h2 + 262144;        // 256*32*4*4   = 131072

    // L1: [256,3,32,32] -> [256,8,16,16]. 512 blocks (img x vhalf) x 512.
    kan_mfma<1><<<512, 512, 0, stream>>>(x, c1_bw, c1_sw, c1_sc, h1);
    // L2: [256,8,16,16] -> [256,16,8,8]. 256 blocks (img) x 512.
    kan_mfma<2><<<256, 512, 0, stream>>>(h1, c2_bw, c2_sw, c2_sc, h2);
    // L3: [256,16,8,8] -> [256,32,4,4]. 512 blocks (img x o-half) x 256.
    kan_mfma<3><<<512, 256, 0, stream>>>(h2, c3_bw, c3_sw, c3_sc, h3);
    // Linear: [256,512] @ [100,512]^T + b.
    linear_coop<<<256, 256, 0, stream>>>(h3, lin_w, lin_b, out);
}

// Round 11
// 104.798 us; speedup vs baseline: 2.0862x; 1.1753x over previous
//
#include <hip/hip_runtime.h>
#include <math.h>

// ---------------------------------------------------------------------------
// KAN-Conv CIFAR net on gfx950, round 16.
// r15 (MFMA rewrite) = 123.2us, -25%. Remaining time: ~56us fixed harness
// overhead (r10 calibration: dur 506 vs kernel 450) + staging VALU + 3 launch
// gaps + L3 double-staging (OS=2) + h2/h3 global roundtrips.
// This round: fuse L2+L3+linear into ONE kernel (per-image block, grid 256,
// NT=512) -- all within-block, no global barriers (r10 lesson respected):
//   stage act2+w2 -> L2 MFMA (r15 body) -> pool into 4KB LDS h2 ->
//   stage act3 from LDS (once, both o-halves) -> L3 MFMA (B preloaded from
//   prebuilt global bf16 table w3g, 144 VGPR) -> pool into 2KB LDS h3 ->
//   linear phase (coalesced lin_w rows + shfl reduce).
// LDS phases alias one 58.5KB arena; syncthreads at each handoff.
// Kernel A = r15 L1 verbatim + blocks 0..8 prep w3g ([tap][32] bf16x8).
// Removes 2 launch boundaries, L3 duplicate staging, h2/h3 roundtrips.
// ---------------------------------------------------------------------------

#define BATCH 256

typedef short bf16x8 __attribute__((ext_vector_type(8)));
typedef float f32x4  __attribute__((ext_vector_type(4)));

__device__ __forceinline__ unsigned f2bf(float f) {
    unsigned u = __float_as_uint(f);
    u += 0x7fffu + ((u >> 16) & 1u);       // round-to-nearest-even
    return u >> 16;
}
__device__ __forceinline__ unsigned pk2(float a, float b) {
    return f2bf(a) | (f2bf(b) << 16);
}

__device__ __forceinline__ void bspline_basis(float x, float bs[6]) {
    const float h = 2.0f / 3.0f;
    float g[10];
#pragma unroll
    for (int i = 0; i < 10; ++i) g[i] = (float)(i - 3) * h - 1.0f;
    float b[9];
#pragma unroll
    for (int i = 0; i < 9; ++i) b[i] = (x >= g[i] && x < g[i + 1]) ? 1.0f : 0.0f;
#pragma unroll
    for (int j = 1; j <= 3; ++j) {
        const float inv_d = 1.0f / ((float)j * h);
#pragma unroll
        for (int i = 0; i + j < 9; ++i) {
            float left  = (x - g[i]) * inv_d;
            float right = (g[i + j + 1] - x) * inv_d;
            b[i] = left * b[i] + right * b[i + 1];
        }
    }
#pragma unroll
    for (int i = 0; i < 6; ++i) bs[i] = b[i];
}

// [silu, b0..b5, 0] as 8 bf16 in one uint4.
__device__ __forceinline__ uint4 act_record(float val) {
    float silu = val / (1.0f + __expf(-val));
    float bs[6];
    bspline_basis(val, bs);
    uint4 r;
    r.x = pk2(silu, bs[0]);
    r.y = pk2(bs[1], bs[2]);
    r.z = pk2(bs[3], bs[4]);
    r.w = f2bf(bs[5]);
    return r;
}

__device__ __forceinline__ uint4 fuse_w(const float* bw, const float* sw,
                                        const float* sc, int j) {
    float s = sc[j];
    uint4 r;
    r.x = pk2(bw[j],             sw[j * 6 + 0] * s);
    r.y = pk2(sw[j * 6 + 1] * s, sw[j * 6 + 2] * s);
    r.z = pk2(sw[j * 6 + 3] * s, sw[j * 6 + 4] * s);
    r.w = f2bf(sw[j * 6 + 5] * s);
    return r;
}

// ---------------------------------------------------------------------------
// Kernel A: L1 conv+pool (r15-verbatim) + prep of L3 bf16 weight table w3g.
// grid 512 (img x vhalf) x 512 threads.
// ---------------------------------------------------------------------------
__global__ __launch_bounds__(512, 4) void kan_l1(
        const float* __restrict__ x,
        const float* __restrict__ bw, const float* __restrict__ sw,
        const float* __restrict__ sc,
        const float* __restrict__ bw3, const float* __restrict__ sw3,
        const float* __restrict__ sc3,
        uint4* __restrict__ w3g,
        float* __restrict__ out) {
    constexpr int C = 3, H = 32, W = 32, F = 27, FP = 28, NS = 7;
    constexpr int RT = 18, TC = 34, NT = 512;

    __shared__ uint4 s_act[C * RT * TC];           // 1836 recs = 29.4KB
    __shared__ uint4 s_w[FP * 16];                 // 7.2KB

    const int tid = threadIdx.x;
    const int bid = blockIdx.x;
    const int b   = bid >> 1;
    const int v   = bid & 1;

    // ---- prep w3g (blocks 0..8): [tap][32] bf16x8, j = i (o*144+fp)
    if (bid < 9) {
        int i = bid * NT + tid;
        if (i < 4608) {
            int o = i / 144, fp = i % 144;
            w3g[fp * 32 + o] = fuse_w(bw3, sw3, sc3, i);
        }
    }

    // ---- stage own weights [fp][16] (zeros for pad tap / o>=8)
    for (int i = tid; i < FP * 16; i += NT) {
        int fp = i >> 4, o = i & 15;
        uint4 r = make_uint4(0u, 0u, 0u, 0u);
        if (fp < F && o < 8) r = fuse_w(bw, sw, sc, o * F + fp);
        s_w[i] = r;
    }

    // ---- stage act records
    const int r0 = 16 * v - 1;
    const float* xb = x + (size_t)b * C * H * W;
    for (int i = tid; i < C * RT * TC; i += NT) {
        int cc  = i / (RT * TC);
        int rr  = (i / TC) % RT;
        int col = i % TC;
        int gr = r0 + rr, gc = col - 1;
        float val = 0.0f;
        if ((unsigned)gr < (unsigned)H && (unsigned)gc < (unsigned)W)
            val = xb[(cc * H + gr) * W + gc];
        s_act[i] = act_record(val);
    }
    __syncthreads();

    const int lane = tid & 63;
    const int wv   = tid >> 6;
    const int kg   = lane >> 4;
    const int oc   = lane & 15;
    const int m    = lane & 15;

    bf16x8 bfr[NS];
#pragma unroll
    for (int s = 0; s < NS; ++s)
        bfr[s] = *reinterpret_cast<const bf16x8*>(&s_w[(4 * s + kg) * 16 + oc]);

    int pixoff[4];
#pragma unroll
    for (int t = 0; t < 4; ++t)
        pixoff[t] = (2 * wv + (t >> 1)) * TC + 16 * (t & 1) + m;

    f32x4 acc[4];
#pragma unroll
    for (int t = 0; t < 4; ++t) acc[t] = (f32x4){0.f, 0.f, 0.f, 0.f};

#pragma unroll
    for (int s = 0; s < NS; ++s) {
        int tp = 4 * s + kg;
        tp = (tp > F - 1) ? F - 1 : tp;            // pad tap: B=0 anyway
        int c  = tp / 9;
        int t9 = tp - 9 * c;
        int ky = t9 / 3;
        int kx = t9 - 3 * ky;
        int base = (c * RT + ky) * TC + kx;
#pragma unroll
        for (int t = 0; t < 4; ++t) {
            bf16x8 a = *reinterpret_cast<const bf16x8*>(&s_act[base + pixoff[t]]);
            acc[t] = __builtin_amdgcn_mfma_f32_16x16x32_bf16(a, bfr[s], acc[t], 0, 0, 0);
        }
    }

    if (oc < 8) {
        f32x4 e0, e1;
#pragma unroll
        for (int p = 0; p < 4; ++p) {
            e0[p] = fmaxf(acc[0][p], acc[2][p]);
            e1[p] = fmaxf(acc[1][p], acc[3][p]);
        }
        float* op = out + (((size_t)b * 8 + oc) * 16 + (8 * v + wv)) * 16;
        op[2 * kg]         = fmaxf(e0[0], e0[1]);
        op[2 * kg + 1]     = fmaxf(e0[2], e0[3]);
        op[8 + 2 * kg]     = fmaxf(e1[0], e1[1]);
        op[8 + 2 * kg + 1] = fmaxf(e1[2], e1[3]);
    }
}

// ---------------------------------------------------------------------------
// Kernel B: L2 conv+pool -> L3 conv+pool -> linear, one block per image.
// grid 256 x 512 threads.  LDS arena phases:
//   P1: act2[2592]u4 (0..41471) | w2[1152]u4 (41472..59903)
//   P2: h2[1024]f   (0..4095)   | act3[1600]u4 (4096..29695)
//   P3: h3[512]f    (0..2047)
// ---------------------------------------------------------------------------
__global__ __launch_bounds__(512, 2) void kan_l2l3lin(
        const float* __restrict__ h1,
        const float* __restrict__ bw2, const float* __restrict__ sw2,
        const float* __restrict__ sc2,
        const uint4* __restrict__ w3g,
        const float* __restrict__ lin_w, const float* __restrict__ lin_b,
        float* __restrict__ out) {
    constexpr int NT = 512;
    __shared__ alignas(16) unsigned char s_mem[59904];
    uint4* s_act2 = (uint4*)s_mem;                 // [2592]
    uint4* s_w2   = (uint4*)(s_mem + 41472);       // [1152]
    float* s_h2   = (float*)s_mem;                 // [1024]
    uint4* s_act3 = (uint4*)(s_mem + 4096);        // [1600]
    float* s_h3   = (float*)s_mem;                 // [512]

    const int tid = threadIdx.x;
    const int n   = blockIdx.x;
    const int lane = tid & 63;
    const int wv   = tid >> 6;
    const int kg   = lane >> 4;
    const int oc   = lane & 15;
    const int m    = lane & 15;

    // ---- P1 stage: w2 fused [fp][16]
    for (int i = tid; i < 72 * 16; i += NT) {
        int fp = i >> 4, o = i & 15;
        s_w2[i] = fuse_w(bw2, sw2, sc2, o * 72 + fp);
    }
    // ---- P1 stage: act2 from h1 (8ch x 18 x 18, halo)
    const float* xb = h1 + (size_t)n * 8 * 16 * 16;
    for (int i = tid; i < 8 * 18 * 18; i += NT) {
        int cc  = i / 324;
        int rr  = (i / 18) % 18;
        int col = i % 18;
        int gr = rr - 1, gc = col - 1;
        float val = 0.0f;
        if ((unsigned)gr < 16u && (unsigned)gc < 16u)
            val = xb[(cc * 16 + gr) * 16 + gc];
        s_act2[i] = act_record(val);
    }
    __syncthreads();

    // ---- L2 MFMA (r15 body): NS2=18, 2 row-tiles per wave
    {
        bf16x8 bfr2[18];
#pragma unroll
        for (int s = 0; s < 18; ++s)
            bfr2[s] = *reinterpret_cast<const bf16x8*>(&s_w2[(4 * s + kg) * 16 + oc]);
        const int p0 = (2 * wv) * 18 + m;
        const int p1 = (2 * wv + 1) * 18 + m;
        f32x4 a0 = (f32x4){0.f, 0.f, 0.f, 0.f};
        f32x4 a1 = (f32x4){0.f, 0.f, 0.f, 0.f};
#pragma unroll
        for (int s = 0; s < 18; ++s) {
            int tp = 4 * s + kg;
            int c  = tp / 9;
            int t9 = tp - 9 * c;
            int ky = t9 / 3;
            int kx = t9 - 3 * ky;
            int base = (c * 18 + ky) * 18 + kx;
            bf16x8 av0 = *reinterpret_cast<const bf16x8*>(&s_act2[base + p0]);
            a0 = __builtin_amdgcn_mfma_f32_16x16x32_bf16(av0, bfr2[s], a0, 0, 0, 0);
            bf16x8 av1 = *reinterpret_cast<const bf16x8*>(&s_act2[base + p1]);
            a1 = __builtin_amdgcn_mfma_f32_16x16x32_bf16(av1, bfr2[s], a1, 0, 0, 0);
        }
        float e0 = fmaxf(a0[0], a1[0]);
        float e1 = fmaxf(a0[1], a1[1]);
        float e2 = fmaxf(a0[2], a1[2]);
        float e3 = fmaxf(a0[3], a1[3]);
        __syncthreads();                           // act2/w2 reads done
        // pooled h2: ch=oc, prow=wv, pcols 2kg,2kg+1
        s_h2[(oc * 8 + wv) * 8 + 2 * kg]     = fmaxf(e0, e1);
        s_h2[(oc * 8 + wv) * 8 + 2 * kg + 1] = fmaxf(e2, e3);
    }
    __syncthreads();

    // ---- P2 stage: act3 from LDS h2 (16ch x 10 x 10, halo)
    for (int i = tid; i < 16 * 10 * 10; i += NT) {
        int cc  = i / 100;
        int rr  = (i / 10) % 10;
        int col = i % 10;
        int gr = rr - 1, gc = col - 1;
        float val = 0.0f;
        if ((unsigned)gr < 8u && (unsigned)gc < 8u)
            val = s_h2[(cc * 8 + gr) * 8 + gc];
        s_act3[i] = act_record(val);
    }
    __syncthreads();

    // ---- L3 MFMA: wave wv -> M-tile mt=wv&3, o-half o03=16*(wv>>2)
    {
        const int mt  = wv & 3;
        const int o03 = 16 * (wv >> 2);
        bf16x8 bfr3[36];
#pragma unroll
        for (int s = 0; s < 36; ++s)
            bfr3[s] = *reinterpret_cast<const bf16x8*>(&w3g[(4 * s + kg) * 32 + o03 + oc]);
        const int poff = (2 * mt + (m >> 3)) * 10 + (m & 7);
        f32x4 a3 = (f32x4){0.f, 0.f, 0.f, 0.f};
#pragma unroll
        for (int s = 0; s < 36; ++s) {
            int tp = 4 * s + kg;
            int c  = tp / 9;
            int t9 = tp - 9 * c;
            int ky = t9 / 3;
            int kx = t9 - 3 * ky;
            int base = (c * 10 + ky) * 10 + kx;
            bf16x8 av = *reinterpret_cast<const bf16x8*>(&s_act3[base + poff]);
            a3 = __builtin_amdgcn_mfma_f32_16x16x32_bf16(av, bfr3[s], a3, 0, 0, 0);
        }
        float q0 = fmaxf(a3[0], a3[1]);
        float q1 = fmaxf(a3[2], a3[3]);
        float y0 = fmaxf(q0, __shfl_xor(q0, 32));
        float y1 = fmaxf(q1, __shfl_xor(q1, 32));
        // h3 (bytes 0..2047) is disjoint from act3 (4096+): no pre-sync needed
        if (kg < 2) {
            s_h3[(o03 + oc) * 16 + mt * 4 + 2 * kg]     = y0;
            s_h3[(o03 + oc) * 16 + mt * 4 + 2 * kg + 1] = y1;
        }
    }
    __syncthreads();

    // ---- linear: h3 row in LDS; 8 waves x strided outputs; coalesced w rows
    {
        const float4* hf = (const float4*)s_h3;
        const float4 h0v = hf[lane];
        const float4 h1v = hf[lane + 64];
#pragma unroll 1
        for (int o = wv; o < 100; o += 8) {
            const float4* wr = (const float4*)(lin_w + (size_t)o * 512);
            float4 w0 = wr[lane];
            float4 w1 = wr[lane + 64];
            float p = w0.x * h0v.x + w0.y * h0v.y + w0.z * h0v.z + w0.w * h0v.w
                    + w1.x * h1v.x + w1.y * h1v.y + w1.z * h1v.z + w1.w * h1v.w;
            p += __shfl_xor(p, 32);
            p += __shfl_xor(p, 16);
            p += __shfl_xor(p, 8);
            p += __shfl_xor(p, 4);
            p += __shfl_xor(p, 2);
            p += __shfl_xor(p, 1);
            if (lane == 0) out[(size_t)n * 100 + o] = p + lin_b[o];
        }
    }
}

extern "C" void kernel_launch(void* const* d_in, const int* in_sizes, int n_in,
                              void* d_out, int out_size, void* d_ws, size_t ws_size,
                              hipStream_t stream) {
    const float* x     = (const float*)d_in[0];
    const float* c1_bw = (const float*)d_in[1];
    const float* c1_sw = (const float*)d_in[2];
    const float* c1_sc = (const float*)d_in[3];
    const float* c2_bw = (const float*)d_in[4];
    const float* c2_sw = (const float*)d_in[5];
    const float* c2_sc = (const float*)d_in[6];
    const float* c3_bw = (const float*)d_in[7];
    const float* c3_sw = (const float*)d_in[8];
    const float* c3_sc = (const float*)d_in[9];
    const float* lin_w = (const float*)d_in[10];
    const float* lin_b = (const float*)d_in[11];
    float* out = (float*)d_out;

    float* ws = (float*)d_ws;
    float* h1 = ws;                      // 256*8*16*16 = 524288 floats
    uint4* w3g = (uint4*)(h1 + 524288);  // 4608 records = 73728 B

    // Kernel A: L1 [256,3,32,32] -> h1 [256,8,16,16]; + w3g prep (blocks 0-8).
    kan_l1<<<512, 512, 0, stream>>>(x, c1_bw, c1_sw, c1_sc,
                                    c3_bw, c3_sw, c3_sc, w3g, h1);
    // Kernel B: per-image L2 -> L3 -> linear. 256 blocks x 512.
    kan_l2l3lin<<<256, 512, 0, stream>>>(h1, c2_bw, c2_sw, c2_sc,
                                         w3g, lin_w, lin_b, out);
}